// Round 2
// baseline (439.749 us; speedup 1.0000x reference)
//
#include <hip/hip_runtime.h>

// DynamicConv2d: B=64, C=8, H=W=256, OUT_C=8, K=3, IN_FEAT=8
// out[b,oc,h,w] = sum_{ic,kh,kw} x[b,ic,h+kh-1,w+kw-1] *
//                 ( dot(dw[b,oc,:], Wg[ic*9+kh*3+kw,:]) + bg[ic*9+kh*3+kw] )

#define HC   65536   // H*W
#define WW   256
#define RPB  8       // rows per block (fused fallback only)

// clang native 4-float vector — required by __builtin_nontemporal_store
// (HIP's float4 is a class type the builtin rejects).
typedef float floatx4 __attribute__((ext_vector_type(4)));

// ---------------------------------------------------------------------------
// Kernel 1: materialize per-sample conv weights into d_ws with layout
//   kern[b][ic][kh][kw][oc]  (so conv reads 72 contiguous floats per (b,ic))
// ---------------------------------------------------------------------------
__global__ __launch_bounds__(576) void gen_kernels(
    const float* __restrict__ dw,   // (B, 8, 8)
    const float* __restrict__ Wg,   // (72, 8)
    const float* __restrict__ bg,   // (72,)
    float* __restrict__ kern)       // (B, 576)
{
    const int b = blockIdx.x;
    const int j = threadIdx.x;
    if (j >= 576) return;
    const int ic   = j / 72;
    const int rem  = j % 72;
    const int kh   = rem / 24;
    const int rem2 = rem % 24;
    const int kw   = rem2 / 8;
    const int oc   = rem2 % 8;
    const int o    = ic * 9 + kh * 3 + kw;   // lin output index

    const float* d = dw + b * 64 + oc * 8;
    const float* g = Wg + o * 8;
    float v = bg[o];
#pragma unroll
    for (int i = 0; i < 8; ++i) v = fmaf(d[i], g[i], v);
    kern[b * 576 + j] = v;
}

// ---------------------------------------------------------------------------
// Kernel 2: the conv. Block = (sample b) x (4-row tile). 256 threads = 4
// waves; each wave owns ONE output row, each lane owns 4 consecutive
// columns (64 lanes x 4 = 256 = W). acc[4 col][8 oc] = 32 VGPRs, so the
// kernel fits <=64 VGPRs -> 32 waves/CU (vs 68 VGPR / 16 waves before).
// Loads: one dwordx4 + two halo scalars per (ic, kh) instead of 3 scalar
// loads per column. Column guards exist only at the true image edge
// (lane 0 left, lane 63 right) because w4-1 / w4+4 are interior otherwise.
// ---------------------------------------------------------------------------
__global__ __launch_bounds__(256, 8) void dyn_conv_v4(
    const float* __restrict__ x,     // (B, 8, 256, 256)
    const float* __restrict__ kern,  // (B, 576) in [ic][kh][kw][oc] layout
    float* __restrict__ out)         // (B, 8, 256, 256)
{
    const int b    = blockIdx.y;
    const int wv   = threadIdx.x >> 6;       // wave id 0..3
    const int lane = threadIdx.x & 63;
    const int h    = blockIdx.x * 4 + wv;    // this wave's output row
    const int w4   = lane << 2;              // first of 4 owned columns

    const float* xb = x + (size_t)b * 8 * HC;
    const float* Kb = kern + b * 576;
    float*       ob = out + (size_t)b * 8 * HC;

    float acc[4][8];                         // [col][oc] — 32 VGPRs
#pragma unroll
    for (int c = 0; c < 4; ++c)
#pragma unroll
        for (int oc = 0; oc < 8; ++oc) acc[c][oc] = 0.f;

#pragma unroll 1
    for (int ic = 0; ic < 8; ++ic) {
        // 72 wave-uniform weights for this ic -> SGPRs (s_load)
        float wk[72];
        const float* Kic = Kb + ic * 72;
#pragma unroll
        for (int t = 0; t < 72; ++t) wk[t] = Kic[t];

        const float* xch = xb + ic * HC;
#pragma unroll
        for (int kh = 0; kh < 3; ++kh) {
            const int row = h - 1 + kh;      // input row feeding weight row kh
            float x0 = 0.f, x1 = 0.f, x2 = 0.f, x3 = 0.f, xl = 0.f, xr = 0.f;
            if (row >= 0 && row < 256) {     // wave-uniform guard
                const float* xrow = xch + row * WW;
                const floatx4 v = *reinterpret_cast<const floatx4*>(xrow + w4);
                x0 = v.x; x1 = v.y; x2 = v.z; x3 = v.w;
                xl = (w4 > 0)       ? xrow[w4 - 1] : 0.f;  // lane 0 = image edge
                xr = (w4 + 4 < WW)  ? xrow[w4 + 4] : 0.f;  // lane 63 = image edge
            }
            const float* wr = &wk[kh * 24];
#pragma unroll
            for (int oc = 0; oc < 8; ++oc) {
                const float w0 = wr[oc];
                const float w1 = wr[8 + oc];
                const float w2 = wr[16 + oc];
                acc[0][oc] = fmaf(xl, w0, fmaf(x0, w1, fmaf(x1, w2, acc[0][oc])));
                acc[1][oc] = fmaf(x0, w0, fmaf(x1, w1, fmaf(x2, w2, acc[1][oc])));
                acc[2][oc] = fmaf(x1, w0, fmaf(x2, w1, fmaf(x3, w2, acc[2][oc])));
                acc[3][oc] = fmaf(x2, w0, fmaf(x3, w1, fmaf(xr, w2, acc[3][oc])));
            }
        }
    }

    // Store: one nt dwordx4 per oc. Output is write-once — keep it from
    // evicting the L3-resident input.
    const size_t o0 = (size_t)h * WW + w4;
#pragma unroll
    for (int oc = 0; oc < 8; ++oc) {
        floatx4 v;
        v.x = acc[0][oc]; v.y = acc[1][oc]; v.z = acc[2][oc]; v.w = acc[3][oc];
        __builtin_nontemporal_store(
            v, reinterpret_cast<floatx4*>(ob + oc * HC + o0));
    }
}

// ---------------------------------------------------------------------------
// Fallback: fused variant (weights computed into LDS) if ws is too small.
// ---------------------------------------------------------------------------
__global__ __launch_bounds__(256) void dyn_conv_fused(
    const float* __restrict__ x,
    const float* __restrict__ dw,
    const float* __restrict__ Wg,
    const float* __restrict__ bg,
    float* __restrict__ out)
{
    __shared__ float kl[576];
    const int b  = blockIdx.y;
    const int h0 = blockIdx.x * RPB;
    const int w  = threadIdx.x;

    for (int j = threadIdx.x; j < 576; j += 256) {
        const int ic   = j / 72;
        const int rem  = j % 72;
        const int kh   = rem / 24;
        const int rem2 = rem % 24;
        const int kw   = rem2 / 8;
        const int oc   = rem2 % 8;
        const int o    = ic * 9 + kh * 3 + kw;
        const float* d = dw + b * 64 + oc * 8;
        const float* g = Wg + o * 8;
        float v = bg[o];
#pragma unroll
        for (int i = 0; i < 8; ++i) v = fmaf(d[i], g[i], v);
        kl[j] = v;
    }
    __syncthreads();

    const float* xb = x + (size_t)b * 8 * HC;
    float*       ob = out + (size_t)b * 8 * HC;

    float acc[RPB][8];
#pragma unroll
    for (int r = 0; r < RPB; ++r)
#pragma unroll
        for (int oc = 0; oc < 8; ++oc) acc[r][oc] = 0.f;

#pragma unroll 1
    for (int ic = 0; ic < 8; ++ic) {
        float wk[72];
        const float* Kic = &kl[ic * 72];
#pragma unroll
        for (int t = 0; t < 72; ++t) wk[t] = Kic[t];

        const float* xch = xb + ic * HC;
#pragma unroll
        for (int ri = 0; ri < RPB + 2; ++ri) {
            const int row = h0 - 1 + ri;
            float xm = 0.f, xc = 0.f, xp = 0.f;
            if (row >= 0 && row < 256) {
                const float* xr = xch + row * WW;
                xc = xr[w];
                xm = (w > 0)   ? xr[w - 1] : 0.f;
                xp = (w < 255) ? xr[w + 1] : 0.f;
            }
#pragma unroll
            for (int kh = 0; kh < 3; ++kh) {
                const int ro = ri - kh;
                if (ro < 0 || ro >= RPB) continue;
                const float* wr = &wk[kh * 24];
#pragma unroll
                for (int oc = 0; oc < 8; ++oc) {
                    float a = acc[ro][oc];
                    a = fmaf(xm, wr[0 * 8 + oc], a);
                    a = fmaf(xc, wr[1 * 8 + oc], a);
                    a = fmaf(xp, wr[2 * 8 + oc], a);
                    acc[ro][oc] = a;
                }
            }
        }
    }

    const int hw0 = h0 * WW + w;
#pragma unroll
    for (int oc = 0; oc < 8; ++oc) {
        float* orow = ob + oc * HC + hw0;
#pragma unroll
        for (int r = 0; r < RPB; ++r) orow[r * WW] = acc[r][oc];
    }
}

extern "C" void kernel_launch(void* const* d_in, const int* in_sizes, int n_in,
                              void* d_out, int out_size, void* d_ws, size_t ws_size,
                              hipStream_t stream) {
    const float* x  = (const float*)d_in[0];  // (64,8,256,256)
    const float* dw = (const float*)d_in[1];  // (64,8,8)
    const float* Wg = (const float*)d_in[2];  // (72,8)
    const float* bg = (const float*)d_in[3];  // (72,)
    float* out = (float*)d_out;

    if (ws_size >= (size_t)(64 * 576 * sizeof(float))) {
        float* kern = (float*)d_ws;
        gen_kernels<<<dim3(64), dim3(576), 0, stream>>>(dw, Wg, bg, kern);
        const dim3 grid(256 / 4, 64);   // 64 row-tiles (4 rows each) x 64 samples
        dyn_conv_v4<<<grid, dim3(256), 0, stream>>>(x, kern, out);
    } else {
        const dim3 grid(256 / RPB, 64);
        dyn_conv_fused<<<grid, dim3(256), 0, stream>>>(x, dw, Wg, bg, out);
    }
}

// Round 3
// 260.139 us; speedup vs baseline: 1.6904x; 1.6904x over previous
//
#include <hip/hip_runtime.h>

// DynamicConv2d: B=64, C=8, H=W=256, OUT_C=8, K=3, IN_FEAT=8
// out[b,oc,h,w] = sum_{ic,kh,kw} x[b,ic,h+kh-1,w+kw-1] *
//                 ( dot(dw[b,oc,:], Wg[ic*9+kh*3+kw,:]) + bg[ic*9+kh*3+kw] )

#define HC   65536   // H*W
#define WW   256
#define RPB  8       // rows per block (fused fallback only)

typedef float floatx4 __attribute__((ext_vector_type(4)));

// ---------------------------------------------------------------------------
// Kernel 1: materialize per-sample conv weights into d_ws with layout
//   kern[b][ic][kh][kw][oc]  (so conv reads 72 contiguous floats per (b,ic))
// ---------------------------------------------------------------------------
__global__ __launch_bounds__(576) void gen_kernels(
    const float* __restrict__ dw,   // (B, 8, 8)
    const float* __restrict__ Wg,   // (72, 8)
    const float* __restrict__ bg,   // (72,)
    float* __restrict__ kern)       // (B, 576)
{
    const int b = blockIdx.x;
    const int j = threadIdx.x;
    if (j >= 576) return;
    const int ic   = j / 72;
    const int rem  = j % 72;
    const int kh   = rem / 24;
    const int rem2 = rem % 24;
    const int kw   = rem2 / 8;
    const int oc   = rem2 % 8;
    const int o    = ic * 9 + kh * 3 + kw;   // lin output index

    const float* d = dw + b * 64 + oc * 8;
    const float* g = Wg + o * 8;
    float v = bg[o];
#pragma unroll
    for (int i = 0; i < 8; ++i) v = fmaf(d[i], g[i], v);
    kern[b * 576 + j] = v;
}

// ---------------------------------------------------------------------------
// Kernel 2: the conv. Block = (sample b) x (4-row tile). 256 threads = 4
// waves; each wave owns ONE output row, each lane owns 4 consecutive
// columns (64 lanes x 4 = 256 = W). acc[4 col][8 oc] = 32 VGPRs ->
// 84% occupancy (measured). One dwordx4 load per (ic,kh); halo columns
// come from neighbor lanes via shuffle (lane i-1's x3 / lane i+1's x0),
// NOT extra global loads. Lane 0 / lane 63 are the true image edges
// because each wave spans the full 256-px row.
// Stores: PLAIN dwordx4. NT stores measured 4x write amplification
// (16B/lane sectors not merged at TCC: WRITE_SIZE 131->526 MB) — never
// nt-store at sub-64B granularity on gfx950.
// ---------------------------------------------------------------------------
__global__ __launch_bounds__(256, 8) void dyn_conv_v5(
    const float* __restrict__ x,     // (B, 8, 256, 256)
    const float* __restrict__ kern,  // (B, 576) in [ic][kh][kw][oc] layout
    float* __restrict__ out)         // (B, 8, 256, 256)
{
    const int b    = blockIdx.y;
    const int wv   = threadIdx.x >> 6;       // wave id 0..3
    const int lane = threadIdx.x & 63;
    const int h    = blockIdx.x * 4 + wv;    // this wave's output row
    const int w4   = lane << 2;              // first of 4 owned columns

    const float* xb = x + (size_t)b * 8 * HC;
    const float* Kb = kern + b * 576;
    float*       ob = out + (size_t)b * 8 * HC;

    float acc[4][8];                         // [col][oc] — 32 VGPRs
#pragma unroll
    for (int c = 0; c < 4; ++c)
#pragma unroll
        for (int oc = 0; oc < 8; ++oc) acc[c][oc] = 0.f;

#pragma unroll 1
    for (int ic = 0; ic < 8; ++ic) {
        // 72 wave-uniform weights for this ic -> SGPRs
        float wk[72];
        const float* Kic = Kb + ic * 72;
#pragma unroll
        for (int t = 0; t < 72; ++t) wk[t] = Kic[t];

        const float* xch = xb + ic * HC;
#pragma unroll
        for (int kh = 0; kh < 3; ++kh) {
            const int row = h - 1 + kh;      // input row feeding weight row kh
            float x0 = 0.f, x1 = 0.f, x2 = 0.f, x3 = 0.f;
            if (row >= 0 && row < 256) {     // wave-uniform guard
                const float* xrow = xch + row * WW;
                const floatx4 v = *reinterpret_cast<const floatx4*>(xrow + w4);
                x0 = v.x; x1 = v.y; x2 = v.z; x3 = v.w;
            }
            // halo from neighbor lanes (row OOB -> zeros propagate)
            float xl = __shfl_up(x3, 1);     // lane i-1's x3
            float xr = __shfl_down(x0, 1);   // lane i+1's x0
            if (lane == 0)  xl = 0.f;        // left image edge
            if (lane == 63) xr = 0.f;        // right image edge

            const float* wr = &wk[kh * 24];
#pragma unroll
            for (int oc = 0; oc < 8; ++oc) {
                const float w0 = wr[oc];
                const float w1 = wr[8 + oc];
                const float w2 = wr[16 + oc];
                acc[0][oc] = fmaf(xl, w0, fmaf(x0, w1, fmaf(x1, w2, acc[0][oc])));
                acc[1][oc] = fmaf(x0, w0, fmaf(x1, w1, fmaf(x2, w2, acc[1][oc])));
                acc[2][oc] = fmaf(x1, w0, fmaf(x2, w1, fmaf(x3, w2, acc[2][oc])));
                acc[3][oc] = fmaf(x2, w0, fmaf(x3, w1, fmaf(xr, w2, acc[3][oc])));
            }
        }
    }

    // Plain coalesced dwordx4 stores (write-combines to full lines in L2).
    const size_t o0 = (size_t)h * WW + w4;
#pragma unroll
    for (int oc = 0; oc < 8; ++oc) {
        floatx4 v;
        v.x = acc[0][oc]; v.y = acc[1][oc]; v.z = acc[2][oc]; v.w = acc[3][oc];
        *reinterpret_cast<floatx4*>(ob + oc * HC + o0) = v;
    }
}

// ---------------------------------------------------------------------------
// Fallback: fused variant (weights computed into LDS) if ws is too small.
// ---------------------------------------------------------------------------
__global__ __launch_bounds__(256) void dyn_conv_fused(
    const float* __restrict__ x,
    const float* __restrict__ dw,
    const float* __restrict__ Wg,
    const float* __restrict__ bg,
    float* __restrict__ out)
{
    __shared__ float kl[576];
    const int b  = blockIdx.y;
    const int h0 = blockIdx.x * RPB;
    const int w  = threadIdx.x;

    for (int j = threadIdx.x; j < 576; j += 256) {
        const int ic   = j / 72;
        const int rem  = j % 72;
        const int kh   = rem / 24;
        const int rem2 = rem % 24;
        const int kw   = rem2 / 8;
        const int oc   = rem2 % 8;
        const int o    = ic * 9 + kh * 3 + kw;
        const float* d = dw + b * 64 + oc * 8;
        const float* g = Wg + o * 8;
        float v = bg[o];
#pragma unroll
        for (int i = 0; i < 8; ++i) v = fmaf(d[i], g[i], v);
        kl[j] = v;
    }
    __syncthreads();

    const float* xb = x + (size_t)b * 8 * HC;
    float*       ob = out + (size_t)b * 8 * HC;

    float acc[RPB][8];
#pragma unroll
    for (int r = 0; r < RPB; ++r)
#pragma unroll
        for (int oc = 0; oc < 8; ++oc) acc[r][oc] = 0.f;

#pragma unroll 1
    for (int ic = 0; ic < 8; ++ic) {
        float wk[72];
        const float* Kic = &kl[ic * 72];
#pragma unroll
        for (int t = 0; t < 72; ++t) wk[t] = Kic[t];

        const float* xch = xb + ic * HC;
#pragma unroll
        for (int ri = 0; ri < RPB + 2; ++ri) {
            const int row = h0 - 1 + ri;
            float xm = 0.f, xc = 0.f, xp = 0.f;
            if (row >= 0 && row < 256) {
                const float* xr = xch + row * WW;
                xc = xr[w];
                xm = (w > 0)   ? xr[w - 1] : 0.f;
                xp = (w < 255) ? xr[w + 1] : 0.f;
            }
#pragma unroll
            for (int kh = 0; kh < 3; ++kh) {
                const int ro = ri - kh;
                if (ro < 0 || ro >= RPB) continue;
                const float* wr = &kl[0] + ic * 72 + kh * 24;
#pragma unroll
                for (int oc = 0; oc < 8; ++oc) {
                    float a = acc[ro][oc];
                    a = fmaf(xm, wr[0 * 8 + oc], a);
                    a = fmaf(xc, wr[1 * 8 + oc], a);
                    a = fmaf(xp, wr[2 * 8 + oc], a);
                    acc[ro][oc] = a;
                }
            }
        }
    }

    const int hw0 = h0 * WW + w;
#pragma unroll
    for (int oc = 0; oc < 8; ++oc) {
        float* orow = ob + oc * HC + hw0;
#pragma unroll
        for (int r = 0; r < RPB; ++r) orow[r * WW] = acc[r][oc];
    }
}

extern "C" void kernel_launch(void* const* d_in, const int* in_sizes, int n_in,
                              void* d_out, int out_size, void* d_ws, size_t ws_size,
                              hipStream_t stream) {
    const float* x  = (const float*)d_in[0];  // (64,8,256,256)
    const float* dw = (const float*)d_in[1];  // (64,8,8)
    const float* Wg = (const float*)d_in[2];  // (72,8)
    const float* bg = (const float*)d_in[3];  // (72,)
    float* out = (float*)d_out;

    if (ws_size >= (size_t)(64 * 576 * sizeof(float))) {
        float* kern = (float*)d_ws;
        gen_kernels<<<dim3(64), dim3(576), 0, stream>>>(dw, Wg, bg, kern);
        const dim3 grid(256 / 4, 64);   // 64 row-tiles (4 rows each) x 64 samples
        dyn_conv_v5<<<grid, dim3(256), 0, stream>>>(x, kern, out);
    } else {
        const dim3 grid(256 / RPB, 64);
        dyn_conv_fused<<<grid, dim3(256), 0, stream>>>(x, dw, Wg, bg, out);
    }
}